// Round 4
// baseline (117.483 us; speedup 1.0000x reference)
//
#include <hip/hip_runtime.h>
#include <hip/hip_cooperative_groups.h>

namespace cg = cooperative_groups;

// Problem constants: B=8, D=64, H=W=56 (N=3136), K=32
#define BB 8
#define DD 64
#define KK 32
#define NN 3136
#define TPB 448            // 7 waves per block; 3136 / 448 = 7 exactly
#define EPT 7              // elements per thread
#define NBLK (BB * DD)     // 512 blocks, one per (b,d); 2 blocks/CU
#define KCH 8              // k-chunk held in registers (8 x float4 = 32 VGPR)

// Inner math per (k, element):
//   t = s2*(x-c)^2 (exp2 domain) == s2*x^2 + p1*x + p2   (p1=-2*s2*c, p2=s2*c^2)
//   e = exp2(t); den += e; cnum += e*c;  E = x - cnum*rcp(den)
// Params are chunk-loaded into an explicit register array (8 ds_read_b128
// batched -> one lgkm wait per chunk) so the hot loop has NO dependent LDS
// reads. R2/R3 post-mortem: compiler fissioned to VGPR=32 with one ~120-cy
// ds_read wait per inner iteration (~28K cy/wave == measured 41 us).
__global__ __launch_bounds__(TPB, 3) void enc_fused(
    const float* __restrict__ X,          // (B, D, N)
    const float* __restrict__ codewords,  // (K, D)
    const float* __restrict__ scale,      // (K, D)
    const float* __restrict__ fc_w,       // (D, D)
    const float* __restrict__ fc_b,       // (D)
    float* __restrict__ out,              // (B, D, N)
    float* __restrict__ em_sum)           // (B*D) scratch
{
    const int bd = blockIdx.x;            // 0..511
    const int b  = bd >> 6;
    const int d  = bd & (DD - 1);
    const int t  = threadIdx.x;

    __shared__ float4 kp_s[KK];           // {s2, p1, p2, c} per k
    __shared__ float  red[TPB / 64];

    const float LOG2E = 1.4426950408889634f;
    if (t < KK) {
        const float c  = codewords[t * DD + d];
        const float s2 = scale[t * DD + d] * LOG2E;   // exp2 domain
        kp_s[t] = make_float4(s2, -2.0f * s2 * c, s2 * c * c, c);
    }
    __syncthreads();

    const float* Xb = X + bd * NN;
    float x[EPT], x2[EPT], den[EPT], cnum[EPT];
#pragma unroll
    for (int j = 0; j < EPT; ++j) {
        x[j]   = Xb[j * TPB + t];         // coalesced
        x2[j]  = x[j] * x[j];
        den[j] = 0.f;
        cnum[j] = 0.f;
    }

    // logits always <= 0 (scale < 0): no max-subtract; >= ~-45: no denormals.
#pragma unroll
    for (int kc = 0; kc < KK / KCH; ++kc) {
        float4 kp[KCH];                   // register-resident chunk
#pragma unroll
        for (int u = 0; u < KCH; ++u) kp[u] = kp_s[kc * KCH + u];
#pragma unroll
        for (int u = 0; u < KCH; ++u) {
#pragma unroll
            for (int j = 0; j < EPT; ++j) {
                float tt = fmaf(x2[j], kp[u].x, fmaf(x[j], kp[u].y, kp[u].z));
                float e  = __builtin_amdgcn_exp2f(tt);   // raw v_exp_f32
                den[j]  += e;
                cnum[j]  = fmaf(e, kp[u].w, cnum[j]);
            }
        }
    }

    float E[EPT];
    float psum = 0.f;
#pragma unroll
    for (int j = 0; j < EPT; ++j) {
        E[j] = x[j] - cnum[j] * __builtin_amdgcn_rcpf(den[j]);
        psum += E[j];
    }

    // block reduction of sum_n E -> em_sum[bd]
#pragma unroll
    for (int off = 32; off > 0; off >>= 1) psum += __shfl_down(psum, off);
    if ((t & 63) == 0) red[t >> 6] = psum;
    __syncthreads();
    if (t == 0) {
        float s = 0.f;
#pragma unroll
        for (int w = 0; w < TPB / 64; ++w) s += red[w];
        em_sum[bd] = s * (1.0f / KK);      // EM[b,d]
    }

    cg::this_grid().sync();

    // gamma[b,d] = sigmoid(EM[b,:] . fc_w[d,:] + fc_b[d])
    // lane-parallel dot: each lane owns one dp term, 6-step xor butterfly.
    const int lane = t & 63;
    const float p0 = em_sum[b * DD + lane] * fc_w[d * DD + lane]; // coalesced
    float p = p0;
#pragma unroll
    for (int off = 32; off > 0; off >>= 1) p += __shfl_xor(p, off);
    const float acc  = p + fc_b[d];
    const float gate = 1.0f +
        __builtin_amdgcn_rcpf(1.0f + __builtin_amdgcn_exp2f(-acc * LOG2E));

    float* Ob = out + bd * NN;
#pragma unroll
    for (int j = 0; j < EPT; ++j)
        Ob[j * TPB + t] = fmaxf(E[j] * gate, 0.f);     // coalesced
}

extern "C" void kernel_launch(void* const* d_in, const int* in_sizes, int n_in,
                              void* d_out, int out_size, void* d_ws, size_t ws_size,
                              hipStream_t stream) {
    const float* X  = (const float*)d_in[0];
    const float* cw = (const float*)d_in[1];
    const float* sc = (const float*)d_in[2];
    const float* fw = (const float*)d_in[3];
    const float* fb = (const float*)d_in[4];
    float* out = (float*)d_out;
    float* em  = (float*)d_ws;            // 512 floats

    void* args[] = {(void*)&X, (void*)&cw, (void*)&sc, (void*)&fw,
                    (void*)&fb, (void*)&out, (void*)&em};
    hipLaunchCooperativeKernel((const void*)enc_fused, dim3(NBLK), dim3(TPB),
                               args, 0, stream);
}

// Round 5
// 88.541 us; speedup vs baseline: 1.3269x; 1.3269x over previous
//
#include <hip/hip_runtime.h>

// Problem constants: B=8, D=64, H=W=56 (N=3136), K=32
#define BB 8
#define DD 64
#define KK 32
#define NN 3136
#define TPB 448            // 7 waves; 3136 / 448 = 7
#define EPT 7
#define NBLK (BB * DD)     // 512 blocks, one per (b,d)
#define TOTAL (BB * DD * NN)

// ---- Kernel A: softmax-over-K aggregation, E -> ws, em_sum[bd] direct ----
// d is BLOCK-uniform -> codeword/scale columns scalarize into SGPRs (s_load).
// Inner loop: v_sub, v_mul, v_mul, v_exp, v_add, v_fma  — no LDS, no spill.
// Single-pass softmax valid: scale<0 => logits in [-45,0], no under/overflow.
__global__ __launch_bounds__(TPB, 4) void enc_main(
    const float* __restrict__ X,          // (B, D, N)
    const float* __restrict__ codewords,  // (K, D)
    const float* __restrict__ scale,      // (K, D)
    float* __restrict__ E_out,            // (B, D, N) ws
    float* __restrict__ em_sum)           // (B*D)
{
    const int bd = blockIdx.x;
    const int d  = __builtin_amdgcn_readfirstlane(bd & (DD - 1)); // uniform
    const int t  = threadIdx.x;
    __shared__ float red[TPB / 64];

    const float LOG2E = 1.4426950408889634f;
    float c[KK], s2[KK];                  // block-uniform -> SGPRs
#pragma unroll
    for (int k = 0; k < KK; ++k) {
        c[k]  = codewords[k * DD + d];
        s2[k] = scale[k * DD + d] * LOG2E;   // exp2 domain
    }

    const float* Xb = X + bd * NN;
    float x[EPT], den[EPT], cnum[EPT];
#pragma unroll
    for (int j = 0; j < EPT; ++j) {
        x[j] = Xb[j * TPB + t];           // coalesced
        den[j] = 0.f;
        cnum[j] = 0.f;
    }

#pragma unroll
    for (int k = 0; k < KK; ++k) {
#pragma unroll
        for (int j = 0; j < EPT; ++j) {
            float r  = x[j] - c[k];               // sgpr operand
            float r2 = r * r;
            float tt = r2 * s2[k];                // sgpr operand
            float e  = __builtin_amdgcn_exp2f(tt);
            den[j]  += e;
            cnum[j]  = fmaf(e, c[k], cnum[j]);    // sgpr operand
        }
    }

    float psum = 0.f;
#pragma unroll
    for (int j = 0; j < EPT; ++j) {
        // E = sum_k e*r / sum_k e = x - (sum_k e*c)/(sum_k e)
        float E = x[j] - cnum[j] * __builtin_amdgcn_rcpf(den[j]);
        E_out[bd * NN + j * TPB + t] = E;
        psum += E;
    }

    // block reduction of sum_n E -> em_sum[bd] (no atomics: 1 block per bd)
#pragma unroll
    for (int off = 32; off > 0; off >>= 1) psum += __shfl_down(psum, off);
    if ((t & 63) == 0) red[t >> 6] = psum;
    __syncthreads();
    if (t == 0) {
        float s = 0.f;
#pragma unroll
        for (int w = 0; w < TPB / 64; ++w) s += red[w];
        em_sum[bd] = s * (1.0f / KK);     // EM[b,d]
    }
}

// ---- Kernel G: gamma gate for all 512 (b,d) in one block ----
__global__ __launch_bounds__(512) void enc_gate(
    const float* __restrict__ em_sum,     // (B*D)
    const float* __restrict__ fc_w,       // (D, D)
    const float* __restrict__ fc_b,       // (D)
    float* __restrict__ g_out)            // (B*D): 1 + sigmoid(...)
{
    __shared__ float em[BB * DD];
    const int t = threadIdx.x;
    em[t] = em_sum[t];
    __syncthreads();

    const int b = t >> 6, d = t & 63;
    const float LOG2E = 1.4426950408889634f;
    float acc = fc_b[d];
#pragma unroll
    for (int dp = 0; dp < DD; ++dp)
        acc = fmaf(em[b * DD + dp], fc_w[d * DD + dp], acc);
    g_out[t] = 1.0f +
        __builtin_amdgcn_rcpf(1.0f + __builtin_amdgcn_exp2f(-acc * LOG2E));
}

// ---- Kernel B: gate + relu, float4 ----
__global__ __launch_bounds__(256) void enc_apply(
    const float* __restrict__ E_in,       // (B, D, N)
    const float* __restrict__ g,          // (B*D)
    float* __restrict__ out)              // (B, D, N)
{
    const int i  = blockIdx.x * 256 + threadIdx.x;  // float4 index
    const int bd = i / (NN / 4);                    // 4 | NN
    const float gg = g[bd];
    float4 v = ((const float4*)E_in)[i];
    v.x = fmaxf(v.x * gg, 0.f);
    v.y = fmaxf(v.y * gg, 0.f);
    v.z = fmaxf(v.z * gg, 0.f);
    v.w = fmaxf(v.w * gg, 0.f);
    ((float4*)out)[i] = v;
}

extern "C" void kernel_launch(void* const* d_in, const int* in_sizes, int n_in,
                              void* d_out, int out_size, void* d_ws, size_t ws_size,
                              hipStream_t stream) {
    const float* X  = (const float*)d_in[0];
    const float* cw = (const float*)d_in[1];
    const float* sc = (const float*)d_in[2];
    const float* fw = (const float*)d_in[3];
    const float* fb = (const float*)d_in[4];
    float* out = (float*)d_out;

    float* E  = (float*)d_ws;             // TOTAL floats
    float* em = E + TOTAL;                // 512
    float* g  = em + NBLK;                // 512

    enc_main<<<NBLK, TPB, 0, stream>>>(X, cw, sc, E, em);
    enc_gate<<<1, 512, 0, stream>>>(em, fw, fb, g);
    enc_apply<<<TOTAL / (4 * 256), 256, 0, stream>>>(E, g, out);
}

// Round 6
// 84.313 us; speedup vs baseline: 1.3934x; 1.0501x over previous
//
#include <hip/hip_runtime.h>

// Problem constants: B=8, D=64, H=W=56 (N=3136), K=32
#define BB 8
#define DD 64
#define KK 32
#define NN 3136
#define TPB 448            // 7 waves; 3136 / 448 = 7
#define EPT 7
#define NBLK (BB * DD)     // 512 blocks, one per (b,d)
#define TOTAL (BB * DD * NN)

// ---- Kernel A: softmax-over-K aggregation ----
// E -> d_out (in-place gated later), em_sum[bd] -> ws.
// d is BLOCK-uniform -> codeword/scale columns scalarize into SGPRs.
// Single-pass softmax valid: scale<0 => logits in [-45,0], no under/overflow.
__global__ __launch_bounds__(TPB, 4) void enc_main(
    const float* __restrict__ X,          // (B, D, N)
    const float* __restrict__ codewords,  // (K, D)
    const float* __restrict__ scale,      // (K, D)
    float* __restrict__ E_out,            // (B, D, N)  == d_out
    float* __restrict__ em_sum)           // (B*D)
{
    const int bd = blockIdx.x;
    const int d  = __builtin_amdgcn_readfirstlane(bd & (DD - 1)); // uniform
    const int t  = threadIdx.x;
    __shared__ float red[TPB / 64];

    const float LOG2E = 1.4426950408889634f;
    float c[KK], s2[KK];                  // block-uniform -> SGPRs
#pragma unroll
    for (int k = 0; k < KK; ++k) {
        c[k]  = codewords[k * DD + d];
        s2[k] = scale[k * DD + d] * LOG2E;   // exp2 domain
    }

    const float* Xb = X + bd * NN;
    float x[EPT], den[EPT], cnum[EPT];
#pragma unroll
    for (int j = 0; j < EPT; ++j) {
        x[j] = Xb[j * TPB + t];           // coalesced
        den[j] = 0.f;
        cnum[j] = 0.f;
    }

#pragma unroll
    for (int k = 0; k < KK; ++k) {
#pragma unroll
        for (int j = 0; j < EPT; ++j) {
            float r  = x[j] - c[k];               // sgpr operand
            float r2 = r * r;
            float tt = r2 * s2[k];                // sgpr operand
            float e  = __builtin_amdgcn_exp2f(tt);
            den[j]  += e;
            cnum[j]  = fmaf(e, c[k], cnum[j]);    // sgpr operand
        }
    }

    float psum = 0.f;
#pragma unroll
    for (int j = 0; j < EPT; ++j) {
        // E = sum_k e*r / sum_k e = x - (sum_k e*c)/(sum_k e)
        float E = x[j] - cnum[j] * __builtin_amdgcn_rcpf(den[j]);
        E_out[bd * NN + j * TPB + t] = E;
        psum += E;
    }

    // block reduction of sum_n E -> em_sum[bd] (no atomics: 1 block per bd)
#pragma unroll
    for (int off = 32; off > 0; off >>= 1) psum += __shfl_down(psum, off);
    if ((t & 63) == 0) red[t >> 6] = psum;
    __syncthreads();
    if (t == 0) {
        float s = 0.f;
#pragma unroll
        for (int w = 0; w < TPB / 64; ++w) s += red[w];
        em_sum[bd] = s * (1.0f / KK);     // EM[b,d]
    }
}

// ---- Kernel B: inline gamma (per-block lane-dot) + gate + relu, in-place --
// One block per (b,d), same grid as enc_main -> same block->XCD mapping,
// so E re-reads are L2-local. Gamma: 64-wide lane dot + xor butterfly,
// redundantly computed per wave (trivial vs a separate serial kernel).
__global__ __launch_bounds__(256) void enc_apply(
    const float* __restrict__ em_sum,     // (B*D) = EM
    const float* __restrict__ fc_w,       // (D, D)
    const float* __restrict__ fc_b,       // (D)
    float* __restrict__ EO)               // d_out: E in, gated out (in-place)
{
    const int bd = blockIdx.x;
    const int b  = bd >> 6, d = bd & (DD - 1);
    const int t  = threadIdx.x;
    const int lane = t & 63;
    const float LOG2E = 1.4426950408889634f;

    // gamma[b,d] = sigmoid(EM[b,:] . fc_w[d,:] + fc_b[d])
    float p = em_sum[b * DD + lane] * fc_w[d * DD + lane];  // coalesced
#pragma unroll
    for (int off = 32; off > 0; off >>= 1) p += __shfl_xor(p, off);
    const float acc  = p + fc_b[d];
    const float gate = 1.0f +
        __builtin_amdgcn_rcpf(1.0f + __builtin_amdgcn_exp2f(-acc * LOG2E));

    float4* P = (float4*)(EO + bd * NN);  // NN/4 = 784 float4s
    for (int i = t; i < NN / 4; i += 256) {
        float4 v = P[i];
        v.x = fmaxf(v.x * gate, 0.f);
        v.y = fmaxf(v.y * gate, 0.f);
        v.z = fmaxf(v.z * gate, 0.f);
        v.w = fmaxf(v.w * gate, 0.f);
        P[i] = v;
    }
}

extern "C" void kernel_launch(void* const* d_in, const int* in_sizes, int n_in,
                              void* d_out, int out_size, void* d_ws, size_t ws_size,
                              hipStream_t stream) {
    const float* X  = (const float*)d_in[0];
    const float* cw = (const float*)d_in[1];
    const float* sc = (const float*)d_in[2];
    const float* fw = (const float*)d_in[3];
    const float* fb = (const float*)d_in[4];
    float* out = (float*)d_out;
    float* em  = (float*)d_ws;            // 512 floats only

    enc_main<<<NBLK, TPB, 0, stream>>>(X, cw, sc, out, em);
    enc_apply<<<NBLK, 256, 0, stream>>>(em, fw, fb, out);
}